// Round 21
// baseline (2475.189 us; speedup 1.0000x reference)
//
#include <hip/hip_runtime.h>
#include <cstdint>
#include <cstddef>

#define NN 32
#define NODE_ELEMS 1605632  // 8*56*56*64 elements per slot (NHWC); bf16 storage

typedef unsigned __int128 u128;
typedef __attribute__((ext_vector_type(8))) short bf16x8;
typedef __attribute__((ext_vector_type(4))) float f32x4;

// ---------------- host: replicate np.random.default_rng(0).random((32,32)) < 0.25 ----
static void compute_adj(bool adj[NN][NN]) {
  uint32_t pool[4];
  uint32_t hc = 0x43b0d7e5u;
  auto hashmix = [&hc](uint32_t v) -> uint32_t {
    v ^= hc; hc *= 0x931e8875u; v *= hc; v ^= v >> 16; return v;
  };
  auto mix = [](uint32_t x, uint32_t y) -> uint32_t {
    uint32_t r = x * 0xca01f9ddu - y * 0x4973f715u; r ^= r >> 16; return r;
  };
  for (int i = 0; i < 4; i++) pool[i] = hashmix(0u);
  for (int s = 0; s < 4; s++)
    for (int d = 0; d < 4; d++)
      if (s != d) pool[d] = mix(pool[d], hashmix(pool[s]));
  uint32_t hb = 0x8b51f9ddu;
  uint32_t w[8];
  for (int k = 0; k < 8; k++) {
    uint32_t v = pool[k & 3];
    v ^= hb; hb *= 0x58f38dedu; v *= hb; v ^= v >> 16;
    w[k] = v;
  }
  uint64_t s64[4];
  for (int j = 0; j < 4; j++) s64[j] = (uint64_t)w[2 * j] | ((uint64_t)w[2 * j + 1] << 32);
  u128 initstate = ((u128)s64[0] << 64) | s64[1];
  u128 initseq   = ((u128)s64[2] << 64) | s64[3];
  const u128 MULT = ((u128)0x2360ED051FC65DA4ULL << 64) | 0x4385DF649FCCF645ULL;
  u128 state = 0;
  u128 inc = (initseq << 1) | 1;
  state = state * MULT + inc;
  state += initstate;
  state = state * MULT + inc;
  for (int i = 0; i < NN; i++)
    for (int j = 0; j < NN; j++) {
      state = state * MULT + inc;
      uint64_t hi = (uint64_t)(state >> 64), lo = (uint64_t)state;
      unsigned rot = (unsigned)(hi >> 58);
      uint64_t xr = hi ^ lo;
      uint64_t out = (xr >> rot) | (xr << ((64u - rot) & 63u));
      double dv = (double)(out >> 11) * (1.0 / 9007199254740992.0);
      adj[i][j] = (dv < 0.25);
    }
}

// ---------------- device ----------------
struct NodeDesc {
  uint8_t node, npred, slot, bar;   // bar: per-image barrier after this node
  uint8_t pred_slot[31];
  uint8_t pad;
};
struct AllArg { int n; NodeDesc d[NN]; };
struct FinalArg { int nf; uint8_t slot[32]; };

__device__ __forceinline__ float bf2f_lo(unsigned int w) {
  union { unsigned int u; float f; } c; c.u = w << 16; return c.f;
}
__device__ __forceinline__ float bf2f_hi(unsigned int w) {
  union { unsigned int u; float f; } c; c.u = w & 0xFFFF0000u; return c.f;
}
__device__ __forceinline__ float bf2f(unsigned short h) {
  union { unsigned int u; float f; } c; c.u = ((unsigned int)h) << 16; return c.f;
}
__device__ __forceinline__ unsigned short f2bf(float f) {
  union { float f; unsigned int u; } c; c.f = f;
  unsigned int u = c.u + 0x7FFFu + ((c.u >> 16) & 1u);  // RNE
  return (unsigned short)(u >> 16);
}

// ONE persistent kernel for the whole DAG, cooperative-launch-safe (R21).
// R20's 784-block cooperative launch was REJECTED (absmax=454 = poison-in-ws
// signature): validator occupancy uses the conservative 64 KB LDS/CU figure
// -> 1 block/CU at 36.3 KB -> max 256 blocks. R19's plain 784-block launch
// deadlocked for the same underlying reason (non-resident blocks + spin).
// Now: grid = 256 = 8 images x 32 blocks. Image b's 32 blocks land on XCD
// b's 32 CUs (1 block/CU; L2 affinity intact). Each block owns 3-4 of its
// image's 98 tiles (98 = 3*32 + 2) and loops them per node; per-image
// barrier = 32 arrivals (L2-local counter, device-scope atomics, fences).
__global__ __launch_bounds__(256) void net_kernel(
    AllArg g,
    const float* __restrict__ x,
    const float* __restrict__ dwall,
    const float* __restrict__ pwall,
    const float* __restrict__ gmall,
    const float* __restrict__ btall,
    const float* __restrict__ mnall,
    const float* __restrict__ vrall,
    const float* __restrict__ aggw,
    unsigned short* __restrict__ wsb,   // bf16 slots (32) then barrier counters
    unsigned int* __restrict__ cnt)     // 8 per-image counters (zeroed by host)
{
  __shared__ float smem[3840];                          // halo [6r][10c][64ch] fp32
  __shared__ __align__(16) unsigned short pwb[2][4096]; // dbuf pw weights (bf16, swz)
  __shared__ __align__(16) unsigned short tbuf[2048];   // t[32 pos][64 c] (bf16, swz)
  __shared__ float wlds[2][32];                         // dbuf agg weights

  const int b = blockIdx.x & 7;       // image == XCD
  const int c = blockIdx.x >> 3;      // block within image [0,32)
  const int t = threadIdx.x;

  int tiles[4];
  tiles[0] = c; tiles[1] = c + 32; tiles[2] = c + 64;
  int ntiles = 3;
  if (c < 2) { tiles[3] = 96 + c; ntiles = 4; }

  auto stage = [&](int kk2, int bb) {
    const float* pwn = pwall + g.d[kk2].node * 4096;
    #pragma unroll
    for (int i = 0; i < 16; i++) {
      int gidx = t + 256 * i;
      int o = gidx >> 6, cc = gidx & 63;
      pwb[bb][o * 64 + ((((cc >> 3) ^ (o & 7)) << 3) | (cc & 7))] = f2bf(pwn[gidx]);
    }
  };

  stage(0, 0);
  unsigned int barid = 0;   // completed per-image barriers (target = 32*barid)

  for (int kk = 0; kk < g.n; kk++) {
    const NodeDesc nd = g.d[kk];
    const int node = nd.node;

    int dwc, pbase;
    if (nd.npred == 0) { dwc = t >> 2; pbase = (t & 3) * 8; }
    else               { dwc = t & 63; pbase = (t >> 6) * 8; }

    float* wl = wlds[kk & 1];
    if (t < nd.npred) {
      float wv = 1.f / (1.f + expf(-aggw[node * 32 + t]));
      wl[t] = (nd.npred == 1) ? 1.0f : wv;
    }

    const float* k9 = dwall + (node * 64 + dwc) * 9;
    float kk9[9];
    #pragma unroll
    for (int q = 0; q < 9; q++) kk9[q] = k9[q];

    __syncthreads();   // B1: wlds + pwb[kk&1] visible; prev node's LDS use done

    for (int tt = 0; tt < ntiles; tt++) {
      const int j = tiles[tt];
      const int ty = (j / 7) * 4;     // 14 y-tiles of 4 rows
      const int tx = (j % 7) * 8;     // 7 x-tiles of 8 cols

      float tv[8];

      if (nd.npred == 0) {
        // input node: depthwise stride-2 over relu(x), x NCHW [8][64][112][112]
        const float* xb = x + (size_t)(b * 64 + dwc) * 12544;
        #pragma unroll
        for (int jj = 0; jj < 8; jj++) {
          int p = pbase + jj;
          int oy = ty + (p >> 3), ox = tx + (p & 7);
          int iy0 = oy * 2 - 1, ix0 = ox * 2 - 1;
          float s = 0.f;
          #pragma unroll
          for (int dy = 0; dy < 3; dy++) {
            int iy = iy0 + dy;
            if ((unsigned)iy >= 112u) continue;
            const float* row = xb + iy * 112;
            #pragma unroll
            for (int dx = 0; dx < 3; dx++) {
              int ix = ix0 + dx;
              if ((unsigned)ix >= 112u) continue;
              s += fmaxf(row[ix], 0.f) * kk9[dy * 3 + dx];
            }
          }
          tv[jj] = s;
        }
        if (tt == 0 && kk + 1 < g.n) stage(kk + 1, (kk + 1) & 1);
      } else {
        // aggregate + relu into fp32 NHWC halo (480 units of 8 ch = 16 B)
        const int np = nd.npred;
        float sa[2][8];
        int off[2];
        bool inb[2];
        #pragma unroll
        for (int u = 0; u < 2; u++) {
          int idx = t + u * 256;
          bool valid = (u == 0) || (t < 224);
          int pos = idx >> 3, q8 = idx & 7;
          int hy = pos / 10, hx = pos - hy * 10;
          int gy = ty + hy - 1, gx = tx + hx - 1;
          inb[u] = valid && ((unsigned)gy < 56u) && ((unsigned)gx < 56u);
          off[u] = ((b * 56 + gy) * 56 + gx) * 64 + q8 * 8;
          #pragma unroll
          for (int q = 0; q < 8; q++) sa[u][q] = 0.f;
        }
        for (int p0 = 0; p0 < np; p0 += 4) {
          uint4 v[4][2];
          #pragma unroll
          for (int pp = 0; pp < 4; pp++) {
            if (p0 + pp < np) {
              const unsigned short* pb = wsb + (size_t)nd.pred_slot[p0 + pp] * NODE_ELEMS;
              #pragma unroll
              for (int u = 0; u < 2; u++)
                if (inb[u]) v[pp][u] = *(const uint4*)(pb + off[u]);
            }
          }
          #pragma unroll
          for (int pp = 0; pp < 4; pp++) {
            if (p0 + pp < np) {
              float wv = wl[p0 + pp];
              #pragma unroll
              for (int u = 0; u < 2; u++) {
                if (inb[u]) {
                  sa[u][0] = fmaf(wv, bf2f_lo(v[pp][u].x), sa[u][0]);
                  sa[u][1] = fmaf(wv, bf2f_hi(v[pp][u].x), sa[u][1]);
                  sa[u][2] = fmaf(wv, bf2f_lo(v[pp][u].y), sa[u][2]);
                  sa[u][3] = fmaf(wv, bf2f_hi(v[pp][u].y), sa[u][3]);
                  sa[u][4] = fmaf(wv, bf2f_lo(v[pp][u].z), sa[u][4]);
                  sa[u][5] = fmaf(wv, bf2f_hi(v[pp][u].z), sa[u][5]);
                  sa[u][6] = fmaf(wv, bf2f_lo(v[pp][u].w), sa[u][6]);
                  sa[u][7] = fmaf(wv, bf2f_hi(v[pp][u].w), sa[u][7]);
                }
              }
            }
          }
        }
        #pragma unroll
        for (int u = 0; u < 2; u++) {
          int idx = t + u * 256;
          if ((u == 0) || (t < 224)) {
            float4 s0 = make_float4(fmaxf(sa[u][0], 0.f), fmaxf(sa[u][1], 0.f),
                                    fmaxf(sa[u][2], 0.f), fmaxf(sa[u][3], 0.f));
            float4 s1 = make_float4(fmaxf(sa[u][4], 0.f), fmaxf(sa[u][5], 0.f),
                                    fmaxf(sa[u][6], 0.f), fmaxf(sa[u][7], 0.f));
            *(float4*)&smem[idx * 8] = s0;
            *(float4*)&smem[idx * 8 + 4] = s1;
          }
        }
        if (tt == 0 && kk + 1 < g.n) stage(kk + 1, (kk + 1) & 1);
        __syncthreads();   // halo ready
        #pragma unroll
        for (int jj = 0; jj < 8; jj++) {
          int p = pbase + jj;
          int py = p >> 3, px = p & 7;
          const float* r0 = smem + (py * 10 + px) * 64 + dwc;
          tv[jj] = r0[0]    * kk9[0] + r0[64]   * kk9[1] + r0[128]  * kk9[2]
                 + r0[640]  * kk9[3] + r0[704]  * kk9[4] + r0[768]  * kk9[5]
                 + r0[1280] * kk9[6] + r0[1344] * kk9[7] + r0[1408] * kk9[8];
        }
      }

      // t matrix bf16, granule-swizzled: (p,c) -> p*64 + (((c>>3)^(p&7))<<3)|(c&7)
      // prev tile's MFMA frag reads finished at that tile's trailing sync.
      #pragma unroll
      for (int jj = 0; jj < 8; jj++) {
        int p = pbase + jj;
        tbuf[p * 64 + ((((dwc >> 3) ^ (p & 7)) << 3) | (dwc & 7))] = f2bf(tv[jj]);
      }
      __syncthreads();   // t ready; halo reads done

      // MFMA pointwise: D[32 pos][64 oc] = t x pw^T
      const int lane = t & 63;
      const int wave = t >> 6;
      const int mtile = wave & 1;
      const int npair = wave >> 1;
      const int lm = lane & 15;
      const int quad = lane >> 4;
      const unsigned short* pwc = pwb[kk & 1];

      bf16x8 afrag[2];
      #pragma unroll
      for (int ks = 0; ks < 2; ks++) {
        int pos = mtile * 16 + lm;
        int gg = ks * 4 + quad;
        afrag[ks] = *(const bf16x8*)&tbuf[pos * 64 + ((gg ^ (pos & 7)) << 3)];
      }
      f32x4 acc[2];
      #pragma unroll
      for (int nt = 0; nt < 2; nt++) {
        acc[nt] = (f32x4){0.f, 0.f, 0.f, 0.f};
        int oc = (npair * 2 + nt) * 16 + lm;
        #pragma unroll
        for (int ks = 0; ks < 2; ks++) {
          int gg = ks * 4 + quad;
          bf16x8 bfrag = *(const bf16x8*)&pwc[oc * 64 + ((gg ^ (oc & 7)) << 3)];
          acc[nt] = __builtin_amdgcn_mfma_f32_16x16x32_bf16(afrag[ks], bfrag, acc[nt], 0, 0, 0);
        }
      }

      // BN + bf16 slot store. D: col=lane&15 (oc), row=quad*4+reg (pos in tile)
      unsigned short* slotp = wsb + (size_t)nd.slot * NODE_ELEMS;
      #pragma unroll
      for (int nt = 0; nt < 2; nt++) {
        int oc = (npair * 2 + nt) * 16 + lm;
        int gi = node * 64 + oc;
        float inv = gmall[gi] / sqrtf(vrall[gi] + 1e-5f);
        float mn = mnall[gi], btv = btall[gi];
        #pragma unroll
        for (int r = 0; r < 4; r++) {
          int pos = mtile * 16 + quad * 4 + r;
          int gy = ty + (pos >> 3), gx = tx + (pos & 7);
          size_t base = (((size_t)(b * 56 + gy)) * 56 + gx) * 64 + oc;
          slotp[base] = f2bf((acc[nt][r] - mn) * inv + btv);
        }
      }
      __syncthreads();   // frag reads done; tbuf/halo free for next tile
    }

    // per-image barrier at level boundaries: 32 blocks of image b
    if (nd.bar) {
      barid++;
      const unsigned int target = 32u * barid;
      __threadfence();          // release: drain this block's slot stores
      __syncthreads();
      if (t == 0) {
        __hip_atomic_fetch_add(&cnt[b], 1u, __ATOMIC_RELEASE, __HIP_MEMORY_SCOPE_AGENT);
        while (__hip_atomic_load(&cnt[b], __ATOMIC_ACQUIRE, __HIP_MEMORY_SCOPE_AGENT) < target)
          __builtin_amdgcn_s_sleep(1);
      }
      __syncthreads();
      __threadfence();          // acquire
    }
  }
}

// Mean of FINAL bf16 slots (fp32 accumulate) -> NCHW d_out. Block per (b,y) row.
__global__ __launch_bounds__(256) void finalize_kernel(
    FinalArg fa, const unsigned short* __restrict__ wsb,
    float* __restrict__ out, float inv_nf)
{
  __shared__ float lds[57 * 64];
  int by = blockIdx.x;
  int b = by / 56, y = by - b * 56;
  size_t rbase = (((size_t)b * 56 + y) * 56) * 64;  // [x][c]
  for (int i = threadIdx.x; i < 3584; i += 256) {
    float s = 0.f;
    for (int f = 0; f < fa.nf; f++)
      s += bf2f(wsb[(size_t)fa.slot[f] * NODE_ELEMS + rbase + i]);
    int xx = i >> 6, c = i & 63;
    lds[c * 57 + xx] = s * inv_nf;
  }
  __syncthreads();
  float* dst = out + (size_t)b * 64 * 3136 + y * 56;
  for (int i = threadIdx.x; i < 3584; i += 256) {
    int c = i / 56, xx = i - c * 56;
    dst[(size_t)c * 3136 + xx] = lds[c * 57 + xx];
  }
}

// ---------------- launcher ----------------
extern "C" void kernel_launch(void* const* d_in, const int* in_sizes, int n_in,
                              void* d_out, int out_size, void* d_ws, size_t ws_size,
                              hipStream_t stream) {
  (void)in_sizes; (void)n_in; (void)ws_size; (void)out_size;
  const float* x     = (const float*)d_in[0];
  const float* dw    = (const float*)d_in[1];
  const float* pw    = (const float*)d_in[2];
  const float* gamma = (const float*)d_in[3];
  const float* beta  = (const float*)d_in[4];
  const float* mean  = (const float*)d_in[5];
  const float* var   = (const float*)d_in[6];
  const float* aggw  = (const float*)d_in[7];
  unsigned short* wsb = (unsigned short*)d_ws;
  float* out = (float*)d_out;

  bool adj[NN][NN];
  compute_adj(adj);

  int npred[NN], preds[NN][NN], nsucc[NN], ispan[NN], level[NN];
  for (int j = 0; j < NN; j++) {
    npred[j] = 0;
    for (int i = 0; i < j; i++) if (adj[i][j]) preds[j][npred[j]++] = i;
  }
  for (int i = 0; i < NN; i++) {
    nsucc[i] = 0; ispan[i] = NN;
    int mx = -1;
    for (int j = i + 1; j < NN; j++) if (adj[i][j]) { nsucc[i]++; mx = j; }
    if (nsucc[i] > 0) ispan[i] = mx;
  }
  int maxlev = 0;
  for (int j = 0; j < NN; j++) {
    int lv = 0;
    for (int p = 0; p < npred[j]; p++) {
      int cand = level[preds[j][p]] + 1;
      if (cand > lv) lv = cand;
    }
    level[j] = lv;
    if (lv > maxlev) maxlev = lv;
  }
  bool isfinal[NN]; int nf = 0;
  for (int i = 0; i < NN; i++) { isfinal[i] = (ispan[i] >= NN - 1); if (isfinal[i]) nf++; }
  int lastlvl[NN];
  for (int i = 0; i < NN; i++) {
    lastlvl[i] = -1;
    for (int j = i + 1; j < NN; j++) if (adj[i][j] && level[j] > lastlvl[i]) lastlvl[i] = level[j];
  }
  // slot allocation: every node gets a slot; FINAL slots never freed.
  int slot[NN]; bool used[NN];
  for (int s = 0; s < NN; s++) used[s] = false;
  for (int L = 0; L <= maxlev; L++) {
    for (int i = 0; i < NN; i++) {
      if (level[i] != L) continue;
      int s = 0; while (used[s]) s++;
      used[s] = true; slot[i] = s;
    }
    for (int i = 0; i < NN; i++)
      if (level[i] <= L && !isfinal[i] && lastlvl[i] == L)
        used[slot[i]] = false;
  }

  // flat topo list with barrier flags at level boundaries
  AllArg g; g.n = 0;
  for (int L = 0; L <= maxlev; L++) {
    for (int i = 0; i < NN; i++) {
      if (level[i] != L) continue;
      NodeDesc& nd = g.d[g.n++];
      nd.node = (uint8_t)i;
      nd.npred = (uint8_t)npred[i];
      nd.slot = (uint8_t)slot[i];
      nd.bar = 0;
      for (int p = 0; p < npred[i]; p++) nd.pred_slot[p] = (uint8_t)slot[preds[i][p]];
    }
    if (L < maxlev && g.n > 0) g.d[g.n - 1].bar = 1;  // barrier after each level except last
  }

  unsigned int* cnt = (unsigned int*)(wsb + (size_t)NN * NODE_ELEMS);
  hipMemsetAsync(cnt, 0, 8 * sizeof(unsigned int), stream);

  // Cooperative launch, 256 blocks (1/CU even under the conservative 64 KB
  // LDS accounting that rejected R20's 784). Deterministic fallback to a
  // plain launch if the runtime refuses cooperative (same every call).
  void* kargs[] = {
    (void*)&g, (void*)&x, (void*)&dw, (void*)&pw, (void*)&gamma, (void*)&beta,
    (void*)&mean, (void*)&var, (void*)&aggw, (void*)&wsb, (void*)&cnt
  };
  hipError_t ce = hipLaunchCooperativeKernel((void*)net_kernel, dim3(256), dim3(256),
                                             kargs, 0, stream);
  if (ce != hipSuccess) {
    net_kernel<<<256, 256, 0, stream>>>(g, x, dw, pw, gamma, beta,
                                        mean, var, aggw, wsb, cnt);
  }

  float inv_nf = 1.0f / (float)nf;
  FinalArg fa; fa.nf = 0;
  for (int i = 0; i < NN; i++) if (isfinal[i]) fa.slot[fa.nf++] = (uint8_t)slot[i];
  finalize_kernel<<<448, 256, 0, stream>>>(fa, wsb, out, inv_nf);
}

// Round 22
// 1781.728 us; speedup vs baseline: 1.3892x; 1.3892x over previous
//
#include <hip/hip_runtime.h>
#include <cstdint>
#include <cstddef>

#define NN 32
#define NODE_ELEMS 1605632  // 8*56*56*64 elements per slot (NHWC); bf16 storage

typedef unsigned __int128 u128;
typedef __attribute__((ext_vector_type(8))) short bf16x8;
typedef __attribute__((ext_vector_type(4))) float f32x4;

// ---------------- host: replicate np.random.default_rng(0).random((32,32)) < 0.25 ----
static void compute_adj(bool adj[NN][NN]) {
  uint32_t pool[4];
  uint32_t hc = 0x43b0d7e5u;
  auto hashmix = [&hc](uint32_t v) -> uint32_t {
    v ^= hc; hc *= 0x931e8875u; v *= hc; v ^= v >> 16; return v;
  };
  auto mix = [](uint32_t x, uint32_t y) -> uint32_t {
    uint32_t r = x * 0xca01f9ddu - y * 0x4973f715u; r ^= r >> 16; return r;
  };
  for (int i = 0; i < 4; i++) pool[i] = hashmix(0u);
  for (int s = 0; s < 4; s++)
    for (int d = 0; d < 4; d++)
      if (s != d) pool[d] = mix(pool[d], hashmix(pool[s]));
  uint32_t hb = 0x8b51f9ddu;
  uint32_t w[8];
  for (int k = 0; k < 8; k++) {
    uint32_t v = pool[k & 3];
    v ^= hb; hb *= 0x58f38dedu; v *= hb; v ^= v >> 16;
    w[k] = v;
  }
  uint64_t s64[4];
  for (int j = 0; j < 4; j++) s64[j] = (uint64_t)w[2 * j] | ((uint64_t)w[2 * j + 1] << 32);
  u128 initstate = ((u128)s64[0] << 64) | s64[1];
  u128 initseq   = ((u128)s64[2] << 64) | s64[3];
  const u128 MULT = ((u128)0x2360ED051FC65DA4ULL << 64) | 0x4385DF649FCCF645ULL;
  u128 state = 0;
  u128 inc = (initseq << 1) | 1;
  state = state * MULT + inc;
  state += initstate;
  state = state * MULT + inc;
  for (int i = 0; i < NN; i++)
    for (int j = 0; j < NN; j++) {
      state = state * MULT + inc;
      uint64_t hi = (uint64_t)(state >> 64), lo = (uint64_t)state;
      unsigned rot = (unsigned)(hi >> 58);
      uint64_t xr = hi ^ lo;
      uint64_t out = (xr >> rot) | (xr << ((64u - rot) & 63u));
      double dv = (double)(out >> 11) * (1.0 / 9007199254740992.0);
      adj[i][j] = (dv < 0.25);
    }
}

// ---------------- device ----------------
struct NodeDesc {
  uint8_t node, npred, slot, bar;   // bar: per-image barrier after this node
  uint8_t pred_slot[31];
  uint8_t pad;
};
struct AllArg { int n; NodeDesc d[NN]; };
struct FinalArg { int nf; uint8_t slot[32]; };

__device__ __forceinline__ float bf2f_lo(unsigned int w) {
  union { unsigned int u; float f; } c; c.u = w << 16; return c.f;
}
__device__ __forceinline__ float bf2f_hi(unsigned int w) {
  union { unsigned int u; float f; } c; c.u = w & 0xFFFF0000u; return c.f;
}
__device__ __forceinline__ float bf2f(unsigned short h) {
  union { unsigned int u; float f; } c; c.u = ((unsigned int)h) << 16; return c.f;
}
__device__ __forceinline__ unsigned short f2bf(float f) {
  union { float f; unsigned int u; } c; c.f = f;
  unsigned int u = c.u + 0x7FFFu + ((c.u >> 16) & 1u);  // RNE
  return (unsigned short)(u >> 16);
}

// Persistent whole-DAG kernel, cooperative (R22). R21 validated the coop path
// but at 256 blocks x 256 thr = 4 waves/CU the machine starved (VALU 3.2%,
// 2316 us). The validator caps BLOCKS (~64 KB LDS accounting -> 1 block/CU),
// not THREADS: now 1024-thread blocks = 4 tile-groups of 256 -> 16 waves/CU,
// the same residency as R18's best config. Grid = 8 images x 25 blocks = 200
// (validates); 100 group-slots cover 98 tiles. LDS 63.7 KB <= 64 KB: per-group
// bf16 halo (7.5 KB) + per-group tbuf (4 KB) + dbuf pwb (16 KB).
// Image b pinned to XCD b; per-image barrier = 25 arrivals.
__global__ __launch_bounds__(1024) void net_kernel(
    AllArg g,
    const float* __restrict__ x,
    const float* __restrict__ dwall,
    const float* __restrict__ pwall,
    const float* __restrict__ gmall,
    const float* __restrict__ btall,
    const float* __restrict__ mnall,
    const float* __restrict__ vrall,
    const float* __restrict__ aggw,
    unsigned short* __restrict__ wsb,   // bf16 slots (32) then barrier counters
    unsigned int* __restrict__ cnt)     // 8 per-image counters (zeroed by host)
{
  __shared__ unsigned short haloB[4][3840];             // per-group halo [6r][10c][64c] bf16
  __shared__ __align__(16) unsigned short tbufS[4][2048]; // per-group t[32p][64c] bf16 swz
  __shared__ __align__(16) unsigned short pwb[2][4096]; // dbuf pw weights (bf16, swz)
  __shared__ float wlds[2][32];                         // dbuf agg weights

  const int b = blockIdx.x & 7;        // image == XCD
  const int blk = blockIdx.x >> 3;     // block within image [0,25)
  const int tid1k = threadIdx.x;       // 0..1023
  const int grp = tid1k >> 8;          // tile group 0..3
  const int t = tid1k & 255;           // thread within group
  const int j = blk * 4 + grp;         // tile [0,100); valid if < 98
  const bool jvalid = (j < 98);
  const int ty = (j / 7) * 4;          // 14 y-tiles of 4 rows
  const int tx = (j % 7) * 8;          // 7 x-tiles of 8 cols

  unsigned short* halo = haloB[grp];
  unsigned short* tbuf = tbufS[grp];

  auto stage = [&](int kk2, int bb) {   // all 1024 threads cooperate
    const float* pwn = pwall + g.d[kk2].node * 4096;
    #pragma unroll
    for (int i = 0; i < 4; i++) {
      int gidx = tid1k + 1024 * i;
      int o = gidx >> 6, cc = gidx & 63;
      pwb[bb][o * 64 + ((((cc >> 3) ^ (o & 7)) << 3) | (cc & 7))] = f2bf(pwn[gidx]);
    }
  };

  stage(0, 0);
  unsigned int barid = 0;   // completed per-image barriers (target = 25*barid)

  for (int kk = 0; kk < g.n; kk++) {
    const NodeDesc nd = g.d[kk];
    const int node = nd.node;

    int dwc, pbase;
    if (nd.npred == 0) { dwc = t >> 2; pbase = (t & 3) * 8; }
    else               { dwc = t & 63; pbase = (t >> 6) * 8; }

    float* wl = wlds[kk & 1];
    if (tid1k < nd.npred) {
      float wv = 1.f / (1.f + expf(-aggw[node * 32 + tid1k]));
      wl[tid1k] = (nd.npred == 1) ? 1.0f : wv;
    }

    const float* k9 = dwall + (node * 64 + dwc) * 9;
    float kk9[9];
    #pragma unroll
    for (int q = 0; q < 9; q++) kk9[q] = k9[q];

    __syncthreads();   // B1: wlds + pwb[kk&1] visible; prev node's MFMA reads done

    float tv[8];

    if (nd.npred == 0) {
      // input node: depthwise stride-2 over relu(x), x NCHW [8][64][112][112]
      if (jvalid) {
        const float* xb = x + (size_t)(b * 64 + dwc) * 12544;
        #pragma unroll
        for (int jj = 0; jj < 8; jj++) {
          int p = pbase + jj;
          int oy = ty + (p >> 3), ox = tx + (p & 7);
          int iy0 = oy * 2 - 1, ix0 = ox * 2 - 1;
          float s = 0.f;
          #pragma unroll
          for (int dy = 0; dy < 3; dy++) {
            int iy = iy0 + dy;
            if ((unsigned)iy >= 112u) continue;
            const float* row = xb + iy * 112;
            #pragma unroll
            for (int dx = 0; dx < 3; dx++) {
              int ix = ix0 + dx;
              if ((unsigned)ix >= 112u) continue;
              s += fmaxf(row[ix], 0.f) * kk9[dy * 3 + dx];
            }
          }
          tv[jj] = s;
        }
      }
      if (kk + 1 < g.n) stage(kk + 1, (kk + 1) & 1);
    } else {
      // aggregate + relu into bf16 halo (480 units of 8 ch per group)
      const int np = nd.npred;
      if (jvalid) {
        float sa[2][8];
        int off[2];
        bool inb[2];
        #pragma unroll
        for (int u = 0; u < 2; u++) {
          int idx = t + u * 256;
          bool valid = (u == 0) || (t < 224);
          int pos = idx >> 3, q8 = idx & 7;
          int hy = pos / 10, hx = pos - hy * 10;
          int gy = ty + hy - 1, gx = tx + hx - 1;
          inb[u] = valid && ((unsigned)gy < 56u) && ((unsigned)gx < 56u);
          off[u] = ((b * 56 + gy) * 56 + gx) * 64 + q8 * 8;
          #pragma unroll
          for (int q = 0; q < 8; q++) sa[u][q] = 0.f;
        }
        for (int p0 = 0; p0 < np; p0 += 4) {
          uint4 v[4][2];
          #pragma unroll
          for (int pp = 0; pp < 4; pp++) {
            if (p0 + pp < np) {
              const unsigned short* pb = wsb + (size_t)nd.pred_slot[p0 + pp] * NODE_ELEMS;
              #pragma unroll
              for (int u = 0; u < 2; u++)
                if (inb[u]) v[pp][u] = *(const uint4*)(pb + off[u]);
            }
          }
          #pragma unroll
          for (int pp = 0; pp < 4; pp++) {
            if (p0 + pp < np) {
              float wv = wl[p0 + pp];
              #pragma unroll
              for (int u = 0; u < 2; u++) {
                if (inb[u]) {
                  sa[u][0] = fmaf(wv, bf2f_lo(v[pp][u].x), sa[u][0]);
                  sa[u][1] = fmaf(wv, bf2f_hi(v[pp][u].x), sa[u][1]);
                  sa[u][2] = fmaf(wv, bf2f_lo(v[pp][u].y), sa[u][2]);
                  sa[u][3] = fmaf(wv, bf2f_hi(v[pp][u].y), sa[u][3]);
                  sa[u][4] = fmaf(wv, bf2f_lo(v[pp][u].z), sa[u][4]);
                  sa[u][5] = fmaf(wv, bf2f_hi(v[pp][u].z), sa[u][5]);
                  sa[u][6] = fmaf(wv, bf2f_lo(v[pp][u].w), sa[u][6]);
                  sa[u][7] = fmaf(wv, bf2f_hi(v[pp][u].w), sa[u][7]);
                }
              }
            }
          }
        }
        #pragma unroll
        for (int u = 0; u < 2; u++) {
          int idx = t + u * 256;
          if ((u == 0) || (t < 224)) {
            ushort4 h0, h1;
            h0.x = f2bf(fmaxf(sa[u][0], 0.f)); h0.y = f2bf(fmaxf(sa[u][1], 0.f));
            h0.z = f2bf(fmaxf(sa[u][2], 0.f)); h0.w = f2bf(fmaxf(sa[u][3], 0.f));
            h1.x = f2bf(fmaxf(sa[u][4], 0.f)); h1.y = f2bf(fmaxf(sa[u][5], 0.f));
            h1.z = f2bf(fmaxf(sa[u][6], 0.f)); h1.w = f2bf(fmaxf(sa[u][7], 0.f));
            *(ushort4*)&halo[idx * 8] = h0;
            *(ushort4*)&halo[idx * 8 + 4] = h1;
          }
        }
      }
      if (kk + 1 < g.n) stage(kk + 1, (kk + 1) & 1);
      __syncthreads();   // B2: halo ready
      if (jvalid) {
        #pragma unroll
        for (int jj = 0; jj < 8; jj++) {
          int p = pbase + jj;
          int py = p >> 3, px = p & 7;
          const unsigned short* r0 = halo + (py * 10 + px) * 64 + dwc;
          tv[jj] = bf2f(r0[0])    * kk9[0] + bf2f(r0[64])   * kk9[1] + bf2f(r0[128])  * kk9[2]
                 + bf2f(r0[640])  * kk9[3] + bf2f(r0[704])  * kk9[4] + bf2f(r0[768])  * kk9[5]
                 + bf2f(r0[1280]) * kk9[6] + bf2f(r0[1344]) * kk9[7] + bf2f(r0[1408]) * kk9[8];
        }
      }
    }

    // t matrix bf16, granule-swizzled: (p,c) -> p*64 + (((c>>3)^(p&7))<<3)|(c&7)
    if (jvalid) {
      #pragma unroll
      for (int jj = 0; jj < 8; jj++) {
        int p = pbase + jj;
        tbuf[p * 64 + ((((dwc >> 3) ^ (p & 7)) << 3) | (dwc & 7))] = f2bf(tv[jj]);
      }
    }
    __syncthreads();   // B3: t ready; halo reads done

    if (jvalid) {
      // MFMA pointwise: D[32 pos][64 oc] = t x pw^T
      const int lane = t & 63;
      const int wave = t >> 6;
      const int mtile = wave & 1;
      const int npair = wave >> 1;
      const int lm = lane & 15;
      const int quad = lane >> 4;
      const unsigned short* pwc = pwb[kk & 1];

      bf16x8 afrag[2];
      #pragma unroll
      for (int ks = 0; ks < 2; ks++) {
        int pos = mtile * 16 + lm;
        int gg = ks * 4 + quad;
        afrag[ks] = *(const bf16x8*)&tbuf[pos * 64 + ((gg ^ (pos & 7)) << 3)];
      }
      f32x4 acc[2];
      #pragma unroll
      for (int nt = 0; nt < 2; nt++) {
        acc[nt] = (f32x4){0.f, 0.f, 0.f, 0.f};
        int oc = (npair * 2 + nt) * 16 + lm;
        #pragma unroll
        for (int ks = 0; ks < 2; ks++) {
          int gg = ks * 4 + quad;
          bf16x8 bfrag = *(const bf16x8*)&pwc[oc * 64 + ((gg ^ (oc & 7)) << 3)];
          acc[nt] = __builtin_amdgcn_mfma_f32_16x16x32_bf16(afrag[ks], bfrag, acc[nt], 0, 0, 0);
        }
      }

      // BN + bf16 slot store. D: col=lane&15 (oc), row=quad*4+reg (pos in tile)
      unsigned short* slotp = wsb + (size_t)nd.slot * NODE_ELEMS;
      #pragma unroll
      for (int nt = 0; nt < 2; nt++) {
        int oc = (npair * 2 + nt) * 16 + lm;
        int gi = node * 64 + oc;
        float inv = gmall[gi] / sqrtf(vrall[gi] + 1e-5f);
        float mn = mnall[gi], btv = btall[gi];
        #pragma unroll
        for (int r = 0; r < 4; r++) {
          int pos = mtile * 16 + quad * 4 + r;
          int gy = ty + (pos >> 3), gx = tx + (pos & 7);
          size_t base = (((size_t)(b * 56 + gy)) * 56 + gx) * 64 + oc;
          slotp[base] = f2bf((acc[nt][r] - mn) * inv + btv);
        }
      }
    }

    // per-image barrier at level boundaries: 25 blocks of image b
    if (nd.bar) {
      barid++;
      const unsigned int target = 25u * barid;
      __threadfence();          // release: drain this block's slot stores
      __syncthreads();
      if (tid1k == 0) {
        __hip_atomic_fetch_add(&cnt[b], 1u, __ATOMIC_RELEASE, __HIP_MEMORY_SCOPE_AGENT);
        while (__hip_atomic_load(&cnt[b], __ATOMIC_ACQUIRE, __HIP_MEMORY_SCOPE_AGENT) < target)
          __builtin_amdgcn_s_sleep(1);
      }
      __syncthreads();
      __threadfence();          // acquire
    }
  }
}

// Mean of FINAL bf16 slots (fp32 accumulate) -> NCHW d_out. Block per (b,y) row.
__global__ __launch_bounds__(256) void finalize_kernel(
    FinalArg fa, const unsigned short* __restrict__ wsb,
    float* __restrict__ out, float inv_nf)
{
  __shared__ float lds[57 * 64];
  int by = blockIdx.x;
  int b = by / 56, y = by - b * 56;
  size_t rbase = (((size_t)b * 56 + y) * 56) * 64;  // [x][c]
  for (int i = threadIdx.x; i < 3584; i += 256) {
    float s = 0.f;
    for (int f = 0; f < fa.nf; f++)
      s += bf2f(wsb[(size_t)fa.slot[f] * NODE_ELEMS + rbase + i]);
    int xx = i >> 6, c = i & 63;
    lds[c * 57 + xx] = s * inv_nf;
  }
  __syncthreads();
  float* dst = out + (size_t)b * 64 * 3136 + y * 56;
  for (int i = threadIdx.x; i < 3584; i += 256) {
    int c = i / 56, xx = i - c * 56;
    dst[(size_t)c * 3136 + xx] = lds[c * 57 + xx];
  }
}

// ---------------- launcher ----------------
extern "C" void kernel_launch(void* const* d_in, const int* in_sizes, int n_in,
                              void* d_out, int out_size, void* d_ws, size_t ws_size,
                              hipStream_t stream) {
  (void)in_sizes; (void)n_in; (void)ws_size; (void)out_size;
  const float* x     = (const float*)d_in[0];
  const float* dw    = (const float*)d_in[1];
  const float* pw    = (const float*)d_in[2];
  const float* gamma = (const float*)d_in[3];
  const float* beta  = (const float*)d_in[4];
  const float* mean  = (const float*)d_in[5];
  const float* var   = (const float*)d_in[6];
  const float* aggw  = (const float*)d_in[7];
  unsigned short* wsb = (unsigned short*)d_ws;
  float* out = (float*)d_out;

  bool adj[NN][NN];
  compute_adj(adj);

  int npred[NN], preds[NN][NN], nsucc[NN], ispan[NN], level[NN];
  for (int j = 0; j < NN; j++) {
    npred[j] = 0;
    for (int i = 0; i < j; i++) if (adj[i][j]) preds[j][npred[j]++] = i;
  }
  for (int i = 0; i < NN; i++) {
    nsucc[i] = 0; ispan[i] = NN;
    int mx = -1;
    for (int j = i + 1; j < NN; j++) if (adj[i][j]) { nsucc[i]++; mx = j; }
    if (nsucc[i] > 0) ispan[i] = mx;
  }
  int maxlev = 0;
  for (int j = 0; j < NN; j++) {
    int lv = 0;
    for (int p = 0; p < npred[j]; p++) {
      int cand = level[preds[j][p]] + 1;
      if (cand > lv) lv = cand;
    }
    level[j] = lv;
    if (lv > maxlev) maxlev = lv;
  }
  bool isfinal[NN]; int nf = 0;
  for (int i = 0; i < NN; i++) { isfinal[i] = (ispan[i] >= NN - 1); if (isfinal[i]) nf++; }
  int lastlvl[NN];
  for (int i = 0; i < NN; i++) {
    lastlvl[i] = -1;
    for (int j = i + 1; j < NN; j++) if (adj[i][j] && level[j] > lastlvl[i]) lastlvl[i] = level[j];
  }
  // slot allocation: every node gets a slot; FINAL slots never freed.
  int slot[NN]; bool used[NN];
  for (int s = 0; s < NN; s++) used[s] = false;
  for (int L = 0; L <= maxlev; L++) {
    for (int i = 0; i < NN; i++) {
      if (level[i] != L) continue;
      int s = 0; while (used[s]) s++;
      used[s] = true; slot[i] = s;
    }
    for (int i = 0; i < NN; i++)
      if (level[i] <= L && !isfinal[i] && lastlvl[i] == L)
        used[slot[i]] = false;
  }

  // flat topo list with barrier flags at level boundaries
  AllArg g; g.n = 0;
  for (int L = 0; L <= maxlev; L++) {
    for (int i = 0; i < NN; i++) {
      if (level[i] != L) continue;
      NodeDesc& nd = g.d[g.n++];
      nd.node = (uint8_t)i;
      nd.npred = (uint8_t)npred[i];
      nd.slot = (uint8_t)slot[i];
      nd.bar = 0;
      for (int p = 0; p < npred[i]; p++) nd.pred_slot[p] = (uint8_t)slot[preds[i][p]];
    }
    if (L < maxlev && g.n > 0) g.d[g.n - 1].bar = 1;  // barrier after each level except last
  }

  unsigned int* cnt = (unsigned int*)(wsb + (size_t)NN * NODE_ELEMS);
  hipMemsetAsync(cnt, 0, 8 * sizeof(unsigned int), stream);

  // Cooperative launch: 200 blocks x 1024 threads (4 tile-groups of 256).
  // 1 block/CU at 63.7 KB LDS -> validates; 16 waves/CU restores R18-level
  // residency. Deterministic plain-launch fallback (200 < 256 CUs -> all
  // blocks schedule immediately even without the cooperative guarantee).
  void* kargs[] = {
    (void*)&g, (void*)&x, (void*)&dw, (void*)&pw, (void*)&gamma, (void*)&beta,
    (void*)&mean, (void*)&var, (void*)&aggw, (void*)&wsb, (void*)&cnt
  };
  hipError_t ce = hipLaunchCooperativeKernel((void*)net_kernel, dim3(200), dim3(1024),
                                             kargs, 0, stream);
  if (ce != hipSuccess) {
    net_kernel<<<200, 1024, 0, stream>>>(g, x, dw, pw, gamma, beta,
                                         mean, var, aggw, wsb, cnt);
  }

  float inv_nf = 1.0f / (float)nf;
  FinalArg fa; fa.nf = 0;
  for (int i = 0; i < NN; i++) if (isfinal[i]) fa.slot[fa.nf++] = (uint8_t)slot[i];
  finalize_kernel<<<448, 256, 0, stream>>>(fa, wsb, out, inv_nf);
}

// Round 23
// 1778.111 us; speedup vs baseline: 1.3920x; 1.0020x over previous
//
#include <hip/hip_runtime.h>
#include <cstdint>
#include <cstddef>

#define NN 32
#define NODE_ELEMS 1605632  // 8*56*56*64 elements per slot (NHWC); bf16 storage

typedef unsigned __int128 u128;
typedef __attribute__((ext_vector_type(8))) short bf16x8;
typedef __attribute__((ext_vector_type(4))) float f32x4;

// ---------------- host: replicate np.random.default_rng(0).random((32,32)) < 0.25 ----
static void compute_adj(bool adj[NN][NN]) {
  uint32_t pool[4];
  uint32_t hc = 0x43b0d7e5u;
  auto hashmix = [&hc](uint32_t v) -> uint32_t {
    v ^= hc; hc *= 0x931e8875u; v *= hc; v ^= v >> 16; return v;
  };
  auto mix = [](uint32_t x, uint32_t y) -> uint32_t {
    uint32_t r = x * 0xca01f9ddu - y * 0x4973f715u; r ^= r >> 16; return r;
  };
  for (int i = 0; i < 4; i++) pool[i] = hashmix(0u);
  for (int s = 0; s < 4; s++)
    for (int d = 0; d < 4; d++)
      if (s != d) pool[d] = mix(pool[d], hashmix(pool[s]));
  uint32_t hb = 0x8b51f9ddu;
  uint32_t w[8];
  for (int k = 0; k < 8; k++) {
    uint32_t v = pool[k & 3];
    v ^= hb; hb *= 0x58f38dedu; v *= hb; v ^= v >> 16;
    w[k] = v;
  }
  uint64_t s64[4];
  for (int j = 0; j < 4; j++) s64[j] = (uint64_t)w[2 * j] | ((uint64_t)w[2 * j + 1] << 32);
  u128 initstate = ((u128)s64[0] << 64) | s64[1];
  u128 initseq   = ((u128)s64[2] << 64) | s64[3];
  const u128 MULT = ((u128)0x2360ED051FC65DA4ULL << 64) | 0x4385DF649FCCF645ULL;
  u128 state = 0;
  u128 inc = (initseq << 1) | 1;
  state = state * MULT + inc;
  state += initstate;
  state = state * MULT + inc;
  for (int i = 0; i < NN; i++)
    for (int j = 0; j < NN; j++) {
      state = state * MULT + inc;
      uint64_t hi = (uint64_t)(state >> 64), lo = (uint64_t)state;
      unsigned rot = (unsigned)(hi >> 58);
      uint64_t xr = hi ^ lo;
      uint64_t out = (xr >> rot) | (xr << ((64u - rot) & 63u));
      double dv = (double)(out >> 11) * (1.0 / 9007199254740992.0);
      adj[i][j] = (dv < 0.25);
    }
}

// ---------------- device ----------------
struct NodeDesc {
  uint8_t node, npred, slot, bar;   // bar: per-image barrier after this node
  uint8_t pred_slot[31];
  uint8_t pad;
};
struct AllArg { int n; NodeDesc d[NN]; };
struct FinalArg { int nf; uint8_t slot[32]; };

__device__ __forceinline__ float bf2f_lo(unsigned int w) {
  union { unsigned int u; float f; } c; c.u = w << 16; return c.f;
}
__device__ __forceinline__ float bf2f_hi(unsigned int w) {
  union { unsigned int u; float f; } c; c.u = w & 0xFFFF0000u; return c.f;
}
__device__ __forceinline__ float bf2f(unsigned short h) {
  union { unsigned int u; float f; } c; c.u = ((unsigned int)h) << 16; return c.f;
}
__device__ __forceinline__ unsigned short f2bf(float f) {
  union { float f; unsigned int u; } c; c.f = f;
  unsigned int u = c.u + 0x7FFFu + ((c.u >> 16) & 1u);  // RNE
  return (unsigned short)(u >> 16);
}

// Persistent whole-DAG kernel, cooperative. R22 restored 16 waves/CU via
// 1024-thread blocks but the allocator's default 8-waves/EU heuristic chose
// VGPR=64 and SPILLED (WRITE 154->312 MB, FETCH +50 MB, 1650 us).
// R23: __launch_bounds__(1024, 4) declares the true occupancy (4 waves/EU =
// 1 block/CU, matching the 64 KB LDS) -> VGPR allowance 128, where the
// kernel's ~96-124 working set fits with zero spill. One knob vs R22.
// Grid = 8 images x 25 blocks = 200 (validates <=256); 4 tile-groups of 256
// threads cover 98 tiles; image b pinned to XCD b; per-image barrier = 25.
__global__ __launch_bounds__(1024, 4) void net_kernel(
    AllArg g,
    const float* __restrict__ x,
    const float* __restrict__ dwall,
    const float* __restrict__ pwall,
    const float* __restrict__ gmall,
    const float* __restrict__ btall,
    const float* __restrict__ mnall,
    const float* __restrict__ vrall,
    const float* __restrict__ aggw,
    unsigned short* __restrict__ wsb,   // bf16 slots (32) then barrier counters
    unsigned int* __restrict__ cnt)     // 8 per-image counters (zeroed by host)
{
  __shared__ unsigned short haloB[4][3840];             // per-group halo [6r][10c][64c] bf16
  __shared__ __align__(16) unsigned short tbufS[4][2048]; // per-group t[32p][64c] bf16 swz
  __shared__ __align__(16) unsigned short pwb[2][4096]; // dbuf pw weights (bf16, swz)
  __shared__ float wlds[2][32];                         // dbuf agg weights

  const int b = blockIdx.x & 7;        // image == XCD
  const int blk = blockIdx.x >> 3;     // block within image [0,25)
  const int tid1k = threadIdx.x;       // 0..1023
  const int grp = tid1k >> 8;          // tile group 0..3
  const int t = tid1k & 255;           // thread within group
  const int j = blk * 4 + grp;         // tile [0,100); valid if < 98
  const bool jvalid = (j < 98);
  const int ty = (j / 7) * 4;          // 14 y-tiles of 4 rows
  const int tx = (j % 7) * 8;          // 7 x-tiles of 8 cols

  unsigned short* halo = haloB[grp];
  unsigned short* tbuf = tbufS[grp];

  auto stage = [&](int kk2, int bb) {   // all 1024 threads cooperate
    const float* pwn = pwall + g.d[kk2].node * 4096;
    #pragma unroll
    for (int i = 0; i < 4; i++) {
      int gidx = tid1k + 1024 * i;
      int o = gidx >> 6, cc = gidx & 63;
      pwb[bb][o * 64 + ((((cc >> 3) ^ (o & 7)) << 3) | (cc & 7))] = f2bf(pwn[gidx]);
    }
  };

  stage(0, 0);
  unsigned int barid = 0;   // completed per-image barriers (target = 25*barid)

  for (int kk = 0; kk < g.n; kk++) {
    const NodeDesc nd = g.d[kk];
    const int node = nd.node;

    int dwc, pbase;
    if (nd.npred == 0) { dwc = t >> 2; pbase = (t & 3) * 8; }
    else               { dwc = t & 63; pbase = (t >> 6) * 8; }

    float* wl = wlds[kk & 1];
    if (tid1k < nd.npred) {
      float wv = 1.f / (1.f + expf(-aggw[node * 32 + tid1k]));
      wl[tid1k] = (nd.npred == 1) ? 1.0f : wv;
    }

    const float* k9 = dwall + (node * 64 + dwc) * 9;
    float kk9[9];
    #pragma unroll
    for (int q = 0; q < 9; q++) kk9[q] = k9[q];

    __syncthreads();   // B1: wlds + pwb[kk&1] visible; prev node's MFMA reads done

    float tv[8];

    if (nd.npred == 0) {
      // input node: depthwise stride-2 over relu(x), x NCHW [8][64][112][112]
      if (jvalid) {
        const float* xb = x + (size_t)(b * 64 + dwc) * 12544;
        #pragma unroll
        for (int jj = 0; jj < 8; jj++) {
          int p = pbase + jj;
          int oy = ty + (p >> 3), ox = tx + (p & 7);
          int iy0 = oy * 2 - 1, ix0 = ox * 2 - 1;
          float s = 0.f;
          #pragma unroll
          for (int dy = 0; dy < 3; dy++) {
            int iy = iy0 + dy;
            if ((unsigned)iy >= 112u) continue;
            const float* row = xb + iy * 112;
            #pragma unroll
            for (int dx = 0; dx < 3; dx++) {
              int ix = ix0 + dx;
              if ((unsigned)ix >= 112u) continue;
              s += fmaxf(row[ix], 0.f) * kk9[dy * 3 + dx];
            }
          }
          tv[jj] = s;
        }
      }
      if (kk + 1 < g.n) stage(kk + 1, (kk + 1) & 1);
    } else {
      // aggregate + relu into bf16 halo (480 units of 8 ch per group)
      const int np = nd.npred;
      if (jvalid) {
        float sa[2][8];
        int off[2];
        bool inb[2];
        #pragma unroll
        for (int u = 0; u < 2; u++) {
          int idx = t + u * 256;
          bool valid = (u == 0) || (t < 224);
          int pos = idx >> 3, q8 = idx & 7;
          int hy = pos / 10, hx = pos - hy * 10;
          int gy = ty + hy - 1, gx = tx + hx - 1;
          inb[u] = valid && ((unsigned)gy < 56u) && ((unsigned)gx < 56u);
          off[u] = ((b * 56 + gy) * 56 + gx) * 64 + q8 * 8;
          #pragma unroll
          for (int q = 0; q < 8; q++) sa[u][q] = 0.f;
        }
        for (int p0 = 0; p0 < np; p0 += 4) {
          uint4 v[4][2];
          #pragma unroll
          for (int pp = 0; pp < 4; pp++) {
            if (p0 + pp < np) {
              const unsigned short* pb = wsb + (size_t)nd.pred_slot[p0 + pp] * NODE_ELEMS;
              #pragma unroll
              for (int u = 0; u < 2; u++)
                if (inb[u]) v[pp][u] = *(const uint4*)(pb + off[u]);
            }
          }
          #pragma unroll
          for (int pp = 0; pp < 4; pp++) {
            if (p0 + pp < np) {
              float wv = wl[p0 + pp];
              #pragma unroll
              for (int u = 0; u < 2; u++) {
                if (inb[u]) {
                  sa[u][0] = fmaf(wv, bf2f_lo(v[pp][u].x), sa[u][0]);
                  sa[u][1] = fmaf(wv, bf2f_hi(v[pp][u].x), sa[u][1]);
                  sa[u][2] = fmaf(wv, bf2f_lo(v[pp][u].y), sa[u][2]);
                  sa[u][3] = fmaf(wv, bf2f_hi(v[pp][u].y), sa[u][3]);
                  sa[u][4] = fmaf(wv, bf2f_lo(v[pp][u].z), sa[u][4]);
                  sa[u][5] = fmaf(wv, bf2f_hi(v[pp][u].z), sa[u][5]);
                  sa[u][6] = fmaf(wv, bf2f_lo(v[pp][u].w), sa[u][6]);
                  sa[u][7] = fmaf(wv, bf2f_hi(v[pp][u].w), sa[u][7]);
                }
              }
            }
          }
        }
        #pragma unroll
        for (int u = 0; u < 2; u++) {
          int idx = t + u * 256;
          if ((u == 0) || (t < 224)) {
            ushort4 h0, h1;
            h0.x = f2bf(fmaxf(sa[u][0], 0.f)); h0.y = f2bf(fmaxf(sa[u][1], 0.f));
            h0.z = f2bf(fmaxf(sa[u][2], 0.f)); h0.w = f2bf(fmaxf(sa[u][3], 0.f));
            h1.x = f2bf(fmaxf(sa[u][4], 0.f)); h1.y = f2bf(fmaxf(sa[u][5], 0.f));
            h1.z = f2bf(fmaxf(sa[u][6], 0.f)); h1.w = f2bf(fmaxf(sa[u][7], 0.f));
            *(ushort4*)&halo[idx * 8] = h0;
            *(ushort4*)&halo[idx * 8 + 4] = h1;
          }
        }
      }
      if (kk + 1 < g.n) stage(kk + 1, (kk + 1) & 1);
      __syncthreads();   // B2: halo ready
      if (jvalid) {
        #pragma unroll
        for (int jj = 0; jj < 8; jj++) {
          int p = pbase + jj;
          int py = p >> 3, px = p & 7;
          const unsigned short* r0 = halo + (py * 10 + px) * 64 + dwc;
          tv[jj] = bf2f(r0[0])    * kk9[0] + bf2f(r0[64])   * kk9[1] + bf2f(r0[128])  * kk9[2]
                 + bf2f(r0[640])  * kk9[3] + bf2f(r0[704])  * kk9[4] + bf2f(r0[768])  * kk9[5]
                 + bf2f(r0[1280]) * kk9[6] + bf2f(r0[1344]) * kk9[7] + bf2f(r0[1408]) * kk9[8];
        }
      }
    }

    // t matrix bf16, granule-swizzled: (p,c) -> p*64 + (((c>>3)^(p&7))<<3)|(c&7)
    if (jvalid) {
      #pragma unroll
      for (int jj = 0; jj < 8; jj++) {
        int p = pbase + jj;
        tbuf[p * 64 + ((((dwc >> 3) ^ (p & 7)) << 3) | (dwc & 7))] = f2bf(tv[jj]);
      }
    }
    __syncthreads();   // B3: t ready; halo reads done

    if (jvalid) {
      // MFMA pointwise: D[32 pos][64 oc] = t x pw^T
      const int lane = t & 63;
      const int wave = t >> 6;
      const int mtile = wave & 1;
      const int npair = wave >> 1;
      const int lm = lane & 15;
      const int quad = lane >> 4;
      const unsigned short* pwc = pwb[kk & 1];

      bf16x8 afrag[2];
      #pragma unroll
      for (int ks = 0; ks < 2; ks++) {
        int pos = mtile * 16 + lm;
        int gg = ks * 4 + quad;
        afrag[ks] = *(const bf16x8*)&tbuf[pos * 64 + ((gg ^ (pos & 7)) << 3)];
      }
      f32x4 acc[2];
      #pragma unroll
      for (int nt = 0; nt < 2; nt++) {
        acc[nt] = (f32x4){0.f, 0.f, 0.f, 0.f};
        int oc = (npair * 2 + nt) * 16 + lm;
        #pragma unroll
        for (int ks = 0; ks < 2; ks++) {
          int gg = ks * 4 + quad;
          bf16x8 bfrag = *(const bf16x8*)&pwc[oc * 64 + ((gg ^ (oc & 7)) << 3)];
          acc[nt] = __builtin_amdgcn_mfma_f32_16x16x32_bf16(afrag[ks], bfrag, acc[nt], 0, 0, 0);
        }
      }

      // BN + bf16 slot store. D: col=lane&15 (oc), row=quad*4+reg (pos in tile)
      unsigned short* slotp = wsb + (size_t)nd.slot * NODE_ELEMS;
      #pragma unroll
      for (int nt = 0; nt < 2; nt++) {
        int oc = (npair * 2 + nt) * 16 + lm;
        int gi = node * 64 + oc;
        float inv = gmall[gi] / sqrtf(vrall[gi] + 1e-5f);
        float mn = mnall[gi], btv = btall[gi];
        #pragma unroll
        for (int r = 0; r < 4; r++) {
          int pos = mtile * 16 + quad * 4 + r;
          int gy = ty + (pos >> 3), gx = tx + (pos & 7);
          size_t base = (((size_t)(b * 56 + gy)) * 56 + gx) * 64 + oc;
          slotp[base] = f2bf((acc[nt][r] - mn) * inv + btv);
        }
      }
    }

    // per-image barrier at level boundaries: 25 blocks of image b
    if (nd.bar) {
      barid++;
      const unsigned int target = 25u * barid;
      __threadfence();          // release: drain this block's slot stores
      __syncthreads();
      if (tid1k == 0) {
        __hip_atomic_fetch_add(&cnt[b], 1u, __ATOMIC_RELEASE, __HIP_MEMORY_SCOPE_AGENT);
        while (__hip_atomic_load(&cnt[b], __ATOMIC_ACQUIRE, __HIP_MEMORY_SCOPE_AGENT) < target)
          __builtin_amdgcn_s_sleep(1);
      }
      __syncthreads();
      __threadfence();          // acquire
    }
  }
}

// Mean of FINAL bf16 slots (fp32 accumulate) -> NCHW d_out. Block per (b,y) row.
__global__ __launch_bounds__(256) void finalize_kernel(
    FinalArg fa, const unsigned short* __restrict__ wsb,
    float* __restrict__ out, float inv_nf)
{
  __shared__ float lds[57 * 64];
  int by = blockIdx.x;
  int b = by / 56, y = by - b * 56;
  size_t rbase = (((size_t)b * 56 + y) * 56) * 64;  // [x][c]
  for (int i = threadIdx.x; i < 3584; i += 256) {
    float s = 0.f;
    for (int f = 0; f < fa.nf; f++)
      s += bf2f(wsb[(size_t)fa.slot[f] * NODE_ELEMS + rbase + i]);
    int xx = i >> 6, c = i & 63;
    lds[c * 57 + xx] = s * inv_nf;
  }
  __syncthreads();
  float* dst = out + (size_t)b * 64 * 3136 + y * 56;
  for (int i = threadIdx.x; i < 3584; i += 256) {
    int c = i / 56, xx = i - c * 56;
    dst[(size_t)c * 3136 + xx] = lds[c * 57 + xx];
  }
}

// ---------------- launcher ----------------
extern "C" void kernel_launch(void* const* d_in, const int* in_sizes, int n_in,
                              void* d_out, int out_size, void* d_ws, size_t ws_size,
                              hipStream_t stream) {
  (void)in_sizes; (void)n_in; (void)ws_size; (void)out_size;
  const float* x     = (const float*)d_in[0];
  const float* dw    = (const float*)d_in[1];
  const float* pw    = (const float*)d_in[2];
  const float* gamma = (const float*)d_in[3];
  const float* beta  = (const float*)d_in[4];
  const float* mean  = (const float*)d_in[5];
  const float* var   = (const float*)d_in[6];
  const float* aggw  = (const float*)d_in[7];
  unsigned short* wsb = (unsigned short*)d_ws;
  float* out = (float*)d_out;

  bool adj[NN][NN];
  compute_adj(adj);

  int npred[NN], preds[NN][NN], nsucc[NN], ispan[NN], level[NN];
  for (int j = 0; j < NN; j++) {
    npred[j] = 0;
    for (int i = 0; i < j; i++) if (adj[i][j]) preds[j][npred[j]++] = i;
  }
  for (int i = 0; i < NN; i++) {
    nsucc[i] = 0; ispan[i] = NN;
    int mx = -1;
    for (int j = i + 1; j < NN; j++) if (adj[i][j]) { nsucc[i]++; mx = j; }
    if (nsucc[i] > 0) ispan[i] = mx;
  }
  int maxlev = 0;
  for (int j = 0; j < NN; j++) {
    int lv = 0;
    for (int p = 0; p < npred[j]; p++) {
      int cand = level[preds[j][p]] + 1;
      if (cand > lv) lv = cand;
    }
    level[j] = lv;
    if (lv > maxlev) maxlev = lv;
  }
  bool isfinal[NN]; int nf = 0;
  for (int i = 0; i < NN; i++) { isfinal[i] = (ispan[i] >= NN - 1); if (isfinal[i]) nf++; }
  int lastlvl[NN];
  for (int i = 0; i < NN; i++) {
    lastlvl[i] = -1;
    for (int j = i + 1; j < NN; j++) if (adj[i][j] && level[j] > lastlvl[i]) lastlvl[i] = level[j];
  }
  // slot allocation: every node gets a slot; FINAL slots never freed.
  int slot[NN]; bool used[NN];
  for (int s = 0; s < NN; s++) used[s] = false;
  for (int L = 0; L <= maxlev; L++) {
    for (int i = 0; i < NN; i++) {
      if (level[i] != L) continue;
      int s = 0; while (used[s]) s++;
      used[s] = true; slot[i] = s;
    }
    for (int i = 0; i < NN; i++)
      if (level[i] <= L && !isfinal[i] && lastlvl[i] == L)
        used[slot[i]] = false;
  }

  // flat topo list with barrier flags at level boundaries
  AllArg g; g.n = 0;
  for (int L = 0; L <= maxlev; L++) {
    for (int i = 0; i < NN; i++) {
      if (level[i] != L) continue;
      NodeDesc& nd = g.d[g.n++];
      nd.node = (uint8_t)i;
      nd.npred = (uint8_t)npred[i];
      nd.slot = (uint8_t)slot[i];
      nd.bar = 0;
      for (int p = 0; p < npred[i]; p++) nd.pred_slot[p] = (uint8_t)slot[preds[i][p]];
    }
    if (L < maxlev && g.n > 0) g.d[g.n - 1].bar = 1;  // barrier after each level except last
  }

  unsigned int* cnt = (unsigned int*)(wsb + (size_t)NN * NODE_ELEMS);
  hipMemsetAsync(cnt, 0, 8 * sizeof(unsigned int), stream);

  // Cooperative launch: 200 blocks x 1024 threads (4 tile-groups of 256).
  // launch_bounds(1024,4): VGPR cap 128 (R22's default heuristic chose 64
  // and spilled ~160 MB of scratch writes). Plain-launch fallback is safe:
  // 200 blocks < 256 CUs at 1 block/CU schedules fully.
  void* kargs[] = {
    (void*)&g, (void*)&x, (void*)&dw, (void*)&pw, (void*)&gamma, (void*)&beta,
    (void*)&mean, (void*)&var, (void*)&aggw, (void*)&wsb, (void*)&cnt
  };
  hipError_t ce = hipLaunchCooperativeKernel((void*)net_kernel, dim3(200), dim3(1024),
                                             kargs, 0, stream);
  if (ce != hipSuccess) {
    net_kernel<<<200, 1024, 0, stream>>>(g, x, dw, pw, gamma, beta,
                                         mean, var, aggw, wsb, cnt);
  }

  float inv_nf = 1.0f / (float)nf;
  FinalArg fa; fa.nf = 0;
  for (int i = 0; i < NN; i++) if (isfinal[i]) fa.slot[fa.nf++] = (uint8_t)slot[i];
  finalize_kernel<<<448, 256, 0, stream>>>(fa, wsb, out, inv_nf);
}

// Round 24
// 599.784 us; speedup vs baseline: 4.1268x; 2.9646x over previous
//
#include <hip/hip_runtime.h>
#include <cstdint>
#include <cstddef>

#define NN 32
#define NODE_ELEMS 1605632  // 8*56*56*64 elements per slot (NHWC); bf16 storage

typedef unsigned __int128 u128;
typedef __attribute__((ext_vector_type(8))) short bf16x8;
typedef __attribute__((ext_vector_type(4))) float f32x4;

// ---------------- host: replicate np.random.default_rng(0).random((32,32)) < 0.25 ----
static void compute_adj(bool adj[NN][NN]) {
  uint32_t pool[4];
  uint32_t hc = 0x43b0d7e5u;
  auto hashmix = [&hc](uint32_t v) -> uint32_t {
    v ^= hc; hc *= 0x931e8875u; v *= hc; v ^= v >> 16; return v;
  };
  auto mix = [](uint32_t x, uint32_t y) -> uint32_t {
    uint32_t r = x * 0xca01f9ddu - y * 0x4973f715u; r ^= r >> 16; return r;
  };
  for (int i = 0; i < 4; i++) pool[i] = hashmix(0u);
  for (int s = 0; s < 4; s++)
    for (int d = 0; d < 4; d++)
      if (s != d) pool[d] = mix(pool[d], hashmix(pool[s]));
  uint32_t hb = 0x8b51f9ddu;
  uint32_t w[8];
  for (int k = 0; k < 8; k++) {
    uint32_t v = pool[k & 3];
    v ^= hb; hb *= 0x58f38dedu; v *= hb; v ^= v >> 16;
    w[k] = v;
  }
  uint64_t s64[4];
  for (int j = 0; j < 4; j++) s64[j] = (uint64_t)w[2 * j] | ((uint64_t)w[2 * j + 1] << 32);
  u128 initstate = ((u128)s64[0] << 64) | s64[1];
  u128 initseq   = ((u128)s64[2] << 64) | s64[3];
  const u128 MULT = ((u128)0x2360ED051FC65DA4ULL << 64) | 0x4385DF649FCCF645ULL;
  u128 state = 0;
  u128 inc = (initseq << 1) | 1;
  state = state * MULT + inc;
  state += initstate;
  state = state * MULT + inc;
  for (int i = 0; i < NN; i++)
    for (int j = 0; j < NN; j++) {
      state = state * MULT + inc;
      uint64_t hi = (uint64_t)(state >> 64), lo = (uint64_t)state;
      unsigned rot = (unsigned)(hi >> 58);
      uint64_t xr = hi ^ lo;
      uint64_t out = (xr >> rot) | (xr << ((64u - rot) & 63u));
      double dv = (double)(out >> 11) * (1.0 / 9007199254740992.0);
      adj[i][j] = (dv < 0.25);
    }
}

// ---------------- device ----------------
struct NodeDesc {
  uint8_t node, npred, slot, flags;
  uint8_t pred_slot[31];
  uint8_t pad;
};
struct GroupArg { int n; NodeDesc d[32]; };   // one launch per LEVEL
struct FinalArg { int nf; uint8_t slot[32]; };

__device__ __forceinline__ float bf2f_lo(unsigned int w) {
  union { unsigned int u; float f; } c; c.u = w << 16; return c.f;
}
__device__ __forceinline__ float bf2f_hi(unsigned int w) {
  union { unsigned int u; float f; } c; c.u = w & 0xFFFF0000u; return c.f;
}
__device__ __forceinline__ float bf2f(unsigned short h) {
  union { unsigned int u; float f; } c; c.u = ((unsigned int)h) << 16; return c.f;
}
__device__ __forceinline__ unsigned short f2bf(float f) {
  union { float f; unsigned int u; } c; c.f = f;
  unsigned int u = c.u + 0x7FFFu + ((c.u >> 16) & 1u);  // RNE
  return (unsigned short)(u >> 16);
}

// R24 = exact revert to R18, the measured best (603 us, absmax 0.0078).
// The persistent whole-DAG experiments (R19-R23) are structurally blocked:
// the cooperative validator caps blocks at 1/CU (64 KB LDS accounting) and
// 16-wave blocks are clamped to 64 VGPRs -> unavoidable spill (WRITE 313 MB)
// or 4-wave starvation (2316 us). Per-level persistent launches keep
// 4-wave/256-thread blocks (VGPR 96, zero spill) at full 784-block residency.
// Within a level: node loop inside the kernel, dbuf bf16 pw weights staged
// during aggregation, MFMA bf16 pointwise, bf16 slots, image b -> XCD b.
__global__ __launch_bounds__(256) void level_kernel(
    GroupArg g,
    const float* __restrict__ x,
    const float* __restrict__ dwall,
    const float* __restrict__ pwall,
    const float* __restrict__ gmall,
    const float* __restrict__ btall,
    const float* __restrict__ mnall,
    const float* __restrict__ vrall,
    const float* __restrict__ aggw,
    unsigned short* __restrict__ wsb)   // bf16 slots
{
  __shared__ float smem[3840];                          // halo [6r][10c][64ch] fp32
  __shared__ __align__(16) unsigned short pwb[2][4096]; // dbuf pw weights (bf16, swz)
  __shared__ __align__(16) unsigned short tbuf[2048];   // t[32 pos][64 c] (bf16, swz)
  __shared__ float wlds[2][32];                         // dbuf agg weights

  const int b = blockIdx.x & 7;       // image == XCD
  const int m = blockIdx.x >> 3;      // tile [0,98)
  const int t = threadIdx.x;
  const int ty = (m / 7) * 4;         // 14 y-tiles of 4 rows
  const int tx = (m % 7) * 8;         // 7 x-tiles of 8 cols

  auto stage = [&](int kk2, int bb) {
    const float* pwn = pwall + g.d[kk2].node * 4096;
    #pragma unroll
    for (int i = 0; i < 16; i++) {
      int gidx = t + 256 * i;
      int o = gidx >> 6, cc = gidx & 63;
      pwb[bb][o * 64 + ((((cc >> 3) ^ (o & 7)) << 3) | (cc & 7))] = f2bf(pwn[gidx]);
    }
  };

  stage(0, 0);

  for (int kk = 0; kk < g.n; kk++) {
    const NodeDesc nd = g.d[kk];
    const int node = nd.node;

    int dwc, pbase;
    if (nd.npred == 0) { dwc = t >> 2; pbase = (t & 3) * 8; }
    else               { dwc = t & 63; pbase = (t >> 6) * 8; }

    float* wl = wlds[kk & 1];
    if (t < nd.npred) {
      float wv = 1.f / (1.f + expf(-aggw[node * 32 + t]));
      wl[t] = (nd.npred == 1) ? 1.0f : wv;
    }
    __syncthreads();   // B1: wlds + pwb[kk&1] visible; tbuf + halo free

    const float* k9 = dwall + (node * 64 + dwc) * 9;
    float kk9[9];
    #pragma unroll
    for (int q = 0; q < 9; q++) kk9[q] = k9[q];

    float tv[8];

    if (nd.npred == 0) {
      // input node: depthwise stride-2 over relu(x), x NCHW [8][64][112][112]
      const float* xb = x + (size_t)(b * 64 + dwc) * 12544;
      #pragma unroll
      for (int jj = 0; jj < 8; jj++) {
        int p = pbase + jj;
        int oy = ty + (p >> 3), ox = tx + (p & 7);
        int iy0 = oy * 2 - 1, ix0 = ox * 2 - 1;
        float s = 0.f;
        #pragma unroll
        for (int dy = 0; dy < 3; dy++) {
          int iy = iy0 + dy;
          if ((unsigned)iy >= 112u) continue;
          const float* row = xb + iy * 112;
          #pragma unroll
          for (int dx = 0; dx < 3; dx++) {
            int ix = ix0 + dx;
            if ((unsigned)ix >= 112u) continue;
            s += fmaxf(row[ix], 0.f) * kk9[dy * 3 + dx];
          }
        }
        tv[jj] = s;
      }
      if (kk + 1 < g.n) stage(kk + 1, (kk + 1) & 1);
    } else {
      // aggregate + relu into fp32 NHWC halo (480 units of 8 ch = 16 B)
      const int np = nd.npred;
      float sa[2][8];
      int off[2];
      bool inb[2];
      #pragma unroll
      for (int u = 0; u < 2; u++) {
        int idx = t + u * 256;
        bool valid = (u == 0) || (t < 224);
        int pos = idx >> 3, q8 = idx & 7;
        int hy = pos / 10, hx = pos - hy * 10;
        int gy = ty + hy - 1, gx = tx + hx - 1;
        inb[u] = valid && ((unsigned)gy < 56u) && ((unsigned)gx < 56u);
        off[u] = ((b * 56 + gy) * 56 + gx) * 64 + q8 * 8;
        #pragma unroll
        for (int q = 0; q < 8; q++) sa[u][q] = 0.f;
      }
      for (int p0 = 0; p0 < np; p0 += 4) {
        uint4 v[4][2];
        #pragma unroll
        for (int pp = 0; pp < 4; pp++) {
          if (p0 + pp < np) {
            const unsigned short* pb = wsb + (size_t)nd.pred_slot[p0 + pp] * NODE_ELEMS;
            #pragma unroll
            for (int u = 0; u < 2; u++)
              if (inb[u]) v[pp][u] = *(const uint4*)(pb + off[u]);
          }
        }
        #pragma unroll
        for (int pp = 0; pp < 4; pp++) {
          if (p0 + pp < np) {
            float wv = wl[p0 + pp];
            #pragma unroll
            for (int u = 0; u < 2; u++) {
              if (inb[u]) {
                sa[u][0] = fmaf(wv, bf2f_lo(v[pp][u].x), sa[u][0]);
                sa[u][1] = fmaf(wv, bf2f_hi(v[pp][u].x), sa[u][1]);
                sa[u][2] = fmaf(wv, bf2f_lo(v[pp][u].y), sa[u][2]);
                sa[u][3] = fmaf(wv, bf2f_hi(v[pp][u].y), sa[u][3]);
                sa[u][4] = fmaf(wv, bf2f_lo(v[pp][u].z), sa[u][4]);
                sa[u][5] = fmaf(wv, bf2f_hi(v[pp][u].z), sa[u][5]);
                sa[u][6] = fmaf(wv, bf2f_lo(v[pp][u].w), sa[u][6]);
                sa[u][7] = fmaf(wv, bf2f_hi(v[pp][u].w), sa[u][7]);
              }
            }
          }
        }
      }
      #pragma unroll
      for (int u = 0; u < 2; u++) {
        int idx = t + u * 256;
        if ((u == 0) || (t < 224)) {
          float4 s0 = make_float4(fmaxf(sa[u][0], 0.f), fmaxf(sa[u][1], 0.f),
                                  fmaxf(sa[u][2], 0.f), fmaxf(sa[u][3], 0.f));
          float4 s1 = make_float4(fmaxf(sa[u][4], 0.f), fmaxf(sa[u][5], 0.f),
                                  fmaxf(sa[u][6], 0.f), fmaxf(sa[u][7], 0.f));
          *(float4*)&smem[idx * 8] = s0;
          *(float4*)&smem[idx * 8 + 4] = s1;
        }
      }
      if (kk + 1 < g.n) stage(kk + 1, (kk + 1) & 1);
      __syncthreads();   // B2: halo ready
      #pragma unroll
      for (int jj = 0; jj < 8; jj++) {
        int p = pbase + jj;
        int py = p >> 3, px = p & 7;
        const float* r0 = smem + (py * 10 + px) * 64 + dwc;
        tv[jj] = r0[0]    * kk9[0] + r0[64]   * kk9[1] + r0[128]  * kk9[2]
               + r0[640]  * kk9[3] + r0[704]  * kk9[4] + r0[768]  * kk9[5]
               + r0[1280] * kk9[6] + r0[1344] * kk9[7] + r0[1408] * kk9[8];
      }
    }

    // t matrix bf16, granule-swizzled: (p,c) -> p*64 + (((c>>3)^(p&7))<<3)|(c&7)
    #pragma unroll
    for (int jj = 0; jj < 8; jj++) {
      int p = pbase + jj;
      tbuf[p * 64 + ((((dwc >> 3) ^ (p & 7)) << 3) | (dwc & 7))] = f2bf(tv[jj]);
    }
    __syncthreads();   // B3: t ready; halo reads done

    // MFMA pointwise: D[32 pos][64 oc] = t x pw^T
    const int lane = t & 63;
    const int wave = t >> 6;
    const int mtile = wave & 1;
    const int npair = wave >> 1;
    const int lm = lane & 15;
    const int quad = lane >> 4;
    const unsigned short* pwc = pwb[kk & 1];

    bf16x8 afrag[2];
    #pragma unroll
    for (int ks = 0; ks < 2; ks++) {
      int pos = mtile * 16 + lm;
      int gg = ks * 4 + quad;
      afrag[ks] = *(const bf16x8*)&tbuf[pos * 64 + ((gg ^ (pos & 7)) << 3)];
    }
    f32x4 acc[2];
    #pragma unroll
    for (int nt = 0; nt < 2; nt++) {
      acc[nt] = (f32x4){0.f, 0.f, 0.f, 0.f};
      int oc = (npair * 2 + nt) * 16 + lm;
      #pragma unroll
      for (int ks = 0; ks < 2; ks++) {
        int gg = ks * 4 + quad;
        bf16x8 bfrag = *(const bf16x8*)&pwc[oc * 64 + ((gg ^ (oc & 7)) << 3)];
        acc[nt] = __builtin_amdgcn_mfma_f32_16x16x32_bf16(afrag[ks], bfrag, acc[nt], 0, 0, 0);
      }
    }

    // BN + bf16 slot store. D: col=lane&15 (oc), row=quad*4+reg (pos in tile)
    unsigned short* slotp = wsb + (size_t)nd.slot * NODE_ELEMS;
    #pragma unroll
    for (int nt = 0; nt < 2; nt++) {
      int oc = (npair * 2 + nt) * 16 + lm;
      int gi = node * 64 + oc;
      float inv = gmall[gi] / sqrtf(vrall[gi] + 1e-5f);
      float mn = mnall[gi], btv = btall[gi];
      #pragma unroll
      for (int r = 0; r < 4; r++) {
        int pos = mtile * 16 + quad * 4 + r;
        int gy = ty + (pos >> 3), gx = tx + (pos & 7);
        size_t base = (((size_t)(b * 56 + gy)) * 56 + gx) * 64 + oc;
        slotp[base] = f2bf((acc[nt][r] - mn) * inv + btv);
      }
    }
    // no trailing barrier: next iteration's B1 orders tbuf/pwb/halo reuse
  }
}

// Mean of FINAL bf16 slots (fp32 accumulate) -> NCHW d_out. Block per (b,y) row.
__global__ __launch_bounds__(256) void finalize_kernel(
    FinalArg fa, const unsigned short* __restrict__ wsb,
    float* __restrict__ out, float inv_nf)
{
  __shared__ float lds[57 * 64];
  int by = blockIdx.x;
  int b = by / 56, y = by - b * 56;
  size_t rbase = (((size_t)b * 56 + y) * 56) * 64;  // [x][c]
  for (int i = threadIdx.x; i < 3584; i += 256) {
    float s = 0.f;
    for (int f = 0; f < fa.nf; f++)
      s += bf2f(wsb[(size_t)fa.slot[f] * NODE_ELEMS + rbase + i]);
    int xx = i >> 6, c = i & 63;
    lds[c * 57 + xx] = s * inv_nf;
  }
  __syncthreads();
  float* dst = out + (size_t)b * 64 * 3136 + y * 56;
  for (int i = threadIdx.x; i < 3584; i += 256) {
    int c = i / 56, xx = i - c * 56;
    dst[(size_t)c * 3136 + xx] = lds[c * 57 + xx];
  }
}

// ---------------- launcher ----------------
extern "C" void kernel_launch(void* const* d_in, const int* in_sizes, int n_in,
                              void* d_out, int out_size, void* d_ws, size_t ws_size,
                              hipStream_t stream) {
  (void)in_sizes; (void)n_in; (void)ws_size; (void)out_size;
  const float* x     = (const float*)d_in[0];
  const float* dw    = (const float*)d_in[1];
  const float* pw    = (const float*)d_in[2];
  const float* gamma = (const float*)d_in[3];
  const float* beta  = (const float*)d_in[4];
  const float* mean  = (const float*)d_in[5];
  const float* var   = (const float*)d_in[6];
  const float* aggw  = (const float*)d_in[7];
  unsigned short* wsb = (unsigned short*)d_ws;
  float* out = (float*)d_out;

  bool adj[NN][NN];
  compute_adj(adj);

  int npred[NN], preds[NN][NN], nsucc[NN], ispan[NN], level[NN];
  for (int j = 0; j < NN; j++) {
    npred[j] = 0;
    for (int i = 0; i < j; i++) if (adj[i][j]) preds[j][npred[j]++] = i;
  }
  for (int i = 0; i < NN; i++) {
    nsucc[i] = 0; ispan[i] = NN;
    int mx = -1;
    for (int j = i + 1; j < NN; j++) if (adj[i][j]) { nsucc[i]++; mx = j; }
    if (nsucc[i] > 0) ispan[i] = mx;
  }
  int maxlev = 0;
  for (int j = 0; j < NN; j++) {
    int lv = 0;
    for (int p = 0; p < npred[j]; p++) {
      int cand = level[preds[j][p]] + 1;
      if (cand > lv) lv = cand;
    }
    level[j] = lv;
    if (lv > maxlev) maxlev = lv;
  }
  bool isfinal[NN]; int nf = 0;
  for (int i = 0; i < NN; i++) { isfinal[i] = (ispan[i] >= NN - 1); if (isfinal[i]) nf++; }
  int lastlvl[NN];
  for (int i = 0; i < NN; i++) {
    lastlvl[i] = -1;
    for (int j = i + 1; j < NN; j++) if (adj[i][j] && level[j] > lastlvl[i]) lastlvl[i] = level[j];
  }
  // slot allocation: every node gets a slot; FINAL slots never freed.
  int slot[NN]; bool used[NN];
  for (int s = 0; s < NN; s++) used[s] = false;
  for (int L = 0; L <= maxlev; L++) {
    for (int i = 0; i < NN; i++) {
      if (level[i] != L) continue;
      int s = 0; while (used[s]) s++;
      used[s] = true; slot[i] = s;
    }
    for (int i = 0; i < NN; i++)
      if (level[i] <= L && !isfinal[i] && lastlvl[i] == L)
        used[slot[i]] = false;
  }

  float inv_nf = 1.0f / (float)nf;

  for (int L = 0; L <= maxlev; L++) {
    GroupArg g; g.n = 0;
    for (int i = 0; i < NN; i++) {
      if (level[i] != L) continue;
      NodeDesc& nd = g.d[g.n++];
      nd.node = (uint8_t)i;
      nd.npred = (uint8_t)npred[i];
      nd.slot = (uint8_t)slot[i];
      nd.flags = 0;
      for (int p = 0; p < npred[i]; p++) nd.pred_slot[p] = (uint8_t)slot[preds[i][p]];
    }
    if (g.n > 0) {
      level_kernel<<<784, 256, 0, stream>>>(g, x, dw, pw, gamma, beta,
                                            mean, var, aggw, wsb);
    }
  }

  FinalArg fa; fa.nf = 0;
  for (int i = 0; i < NN; i++) if (isfinal[i]) fa.slot[fa.nf++] = (uint8_t)slot[i];
  finalize_kernel<<<448, 256, 0, stream>>>(fa, wsb, out, inv_nf);
}